// Round 5
// baseline (36238.007 us; speedup 1.0000x reference)
//
#include <hip/hip_runtime.h>

#define Bv 128
#define Tv 256
#define Vv 512
#define Hv 1024
#define FH 4096   // 4*H
#define TD 255    // T-1 decoder steps

typedef unsigned short ushort_t;
typedef __attribute__((ext_vector_type(8))) short bf16x8;
typedef __attribute__((ext_vector_type(4))) float f32x4;

__device__ __forceinline__ ushort_t f2bf(float f) {
    unsigned u = __float_as_uint(f);
    unsigned r = (u + 0x7fffu + ((u >> 16) & 1u)) >> 16;
    return (ushort_t)r;
}
__device__ __forceinline__ float bf2f(ushort_t h) {
    return __uint_as_float(((unsigned)h) << 16);
}
__device__ __forceinline__ float sigm(float x) {
    return 1.0f / (1.0f + expf(-x));
}

// ---------------------------------------------------------------------------
// Split W [K][N] fp32 into transposed hi/lo bf16 [N][K]
// ---------------------------------------------------------------------------
__global__ __launch_bounds__(256) void wsplit_t(
    const float* __restrict__ W, int K, int N,
    ushort_t* __restrict__ hiT, ushort_t* __restrict__ loT)
{
    __shared__ float ts[32][65];
    const int n0 = blockIdx.x * 64, k0 = blockIdx.y * 32;
    const int tid = threadIdx.x;
#pragma unroll
    for (int i = 0; i < 8; i++) {
        int f = tid + i * 256;
        int k = f >> 6, nn = f & 63;
        ts[k][nn] = W[(size_t)(k0 + k) * N + n0 + nn];
    }
    __syncthreads();
#pragma unroll
    for (int i = 0; i < 8; i++) {
        int f = tid + i * 256;
        int nn = f >> 5, k = f & 31;
        float v = ts[k][nn];
        ushort_t h = f2bf(v);
        ushort_t l = f2bf(v - bf2f(h));
        size_t o = (size_t)(n0 + nn) * K + k0 + k;
        hiT[o] = h;
        loT[o] = l;
    }
}

// ---------------------------------------------------------------------------
__global__ __launch_bounds__(256) void extract_tokens(
    const float* __restrict__ x, int* __restrict__ tok)
{
    int row = blockIdx.x * 4 + (threadIdx.x >> 6);
    int lane = threadIdx.x & 63;
    const float* p = x + (size_t)row * Vv;
    int found = -1;
#pragma unroll
    for (int i = 0; i < 8; i++)
        if (p[lane + i * 64] > 0.5f) found = lane + i * 64;
#pragma unroll
    for (int off = 32; off > 0; off >>= 1) {
        int o = __shfl_down(found, off);
        found = found > o ? found : o;
    }
    if (lane == 0) tok[row] = found;
}

// ---------------------------------------------------------------------------
__global__ void find_eos(const int* __restrict__ tok, int* __restrict__ idx)
{
    int b = threadIdx.x;
    int first = Tv - 1;
    for (int t = Tv - 1; t >= 0; t--)
        if (tok[b * Tv + t] == 1) first = t;
    idx[b] = first;
}

// ---------------------------------------------------------------------------
// Epoch barrier, 256 blocks. ALL barrier traffic is far-atomic RMWs
// (fetch_add) -- arrive, wake (flag increment), and poll -- which execute at
// the LLC coherence point. Data visibility comes from the compiler-generated
// agent fences (release before arrive, acquire after wake). Dirty data per
// step is ~0.3 MB, so the release writeback should be cheap.
// Layout (ints): flag[g] at bar[g*32] (g<8); counters at bar[256+g*32];
// master at bar[512]. Monotonic, no resets.
// ---------------------------------------------------------------------------
__device__ __forceinline__ void gbar(int* bar, int e)
{
    __builtin_amdgcn_fence(__ATOMIC_RELEASE, "agent");
    __syncthreads();
    if (threadIdx.x == 0) {
        const int g = blockIdx.x & 7;
        int old = __hip_atomic_fetch_add(&bar[256 + g * 32], 1,
                                         __ATOMIC_RELAXED, __HIP_MEMORY_SCOPE_AGENT);
        if (old == e * 32 + 31) {                  // last of this group's 32
            int m = __hip_atomic_fetch_add(&bar[512], 1,
                                           __ATOMIC_RELAXED, __HIP_MEMORY_SCOPE_AGENT);
            if (m == e * 8 + 7) {                  // last group: wake all via RMW
#pragma unroll
                for (int gg = 0; gg < 8; gg++)
                    __hip_atomic_fetch_add(&bar[gg * 32], 1,
                                           __ATOMIC_RELAXED, __HIP_MEMORY_SCOPE_AGENT);
            }
        }
        while (__hip_atomic_fetch_add(&bar[g * 32], 0,
                                      __ATOMIC_RELAXED, __HIP_MEMORY_SCOPE_AGENT) < e + 1)
            __builtin_amdgcn_s_sleep(1);
    }
    __syncthreads();
    __builtin_amdgcn_fence(__ATOMIC_ACQUIRE, "agent");
}

// ---------------------------------------------------------------------------
// PERSISTENT fused LSTM v2: 256 blocks x 512 threads (8 waves), 1 block/CU.
// Block = 32 z-cols (8 j x 4 gates) x 64 batches, FULL K=1024:
//   - weights LDS-resident (128 KB, refilled once at decoder switch)
//   - NO cross-block z partials; gate exchange via 8 KB LDS
//   - c-state in registers for the whole 511 steps
//   - cross-block traffic per step: h ping-pong slices only (~0.3 MB dirty)
//   - ONE barrier per step (read h[cur] ... write h[nxt] ... gbar)
// Waves: wm = wave&3 (16-row m-tile), wn = wave>>2 (16-col n-tile).
// ---------------------------------------------------------------------------
struct PArgs {
    const ushort_t *eWhiT, *eWloT, *dWhiT, *dWloT;   // [4096][1024] split
    const float *eWi, *dWi, *eb, *db;
    const int *etok, *dtok, *eidx;
    const ushort_t *hz_hi, *hz_lo;                   // zeroed initial h
    ushort_t *hb0_hi, *hb0_lo, *hb1_hi, *hb1_lo;     // ping-pong h
    ushort_t *hsv_hi, *hsv_lo;                       // encoder h @ eos
    ushort_t *hd_hi, *hd_lo;                         // decoder h history
    int* bar;
};

__global__ __launch_bounds__(512) void lstm_persist(PArgs P)
{
    __shared__ ushort_t wlds[2][128][32][8];   // [hi/lo][kq][c][8] = 131072 B
    __shared__ float z_s[64][33];              // gate exchange, 8448 B

    const int tid  = threadIdx.x;
    const int wave = tid >> 6, lane = tid & 63;
    const int n = lane & 15, quad = lane >> 4;
    const int wm = wave & 3, wn = wave >> 2;
    const int blk = blockIdx.x;
    const int cbj = blk >> 1, bhalf = blk & 1;
    const int j0 = cbj * 8;
    const int b0 = bhalf * 64;
    const int cw = wn * 16 + n;                // this lane's block-col (0..31)

    // ---- one-time (per phase) LDS weight fill: 32 cols x full K ------------
    auto fill_w = [&](const ushort_t* hiT, const ushort_t* loT) {
#pragma unroll
        for (int i = 0; i < 16; i++) {
            int id = tid + i * 512;            // 0..8191 16B chunks
            int half = id >> 12, rem = id & 4095;
            int kq = rem & 127, c = rem >> 7;  // c 0..31 : gate=c>>3, jl=c&7
            const ushort_t* src = half ? loT : hiT;
            bf16x8 v = *(const bf16x8*)(src +
                (size_t)((c >> 3) * Hv + j0 + (c & 7)) * Hv + kq * 8);
            *(bf16x8*)(&wlds[half][kq][c][0]) = v;
        }
    };

    // A fragment: lane reads h row (b0 + wm*16 + n), 8 k per lane per chunk
    const size_t arow = (size_t)(b0 + wm * 16 + n) * Hv + quad * 8;

    // ---- epilogue ownership: 1 (b,j) element per thread --------------------
    const int bl = tid >> 3;                   // 0..63
    const int jl = tid & 7;                    // 0..7
    const int b_e = b0 + bl;
    const int j   = j0 + jl;

    const float eb_0 = P.eb[j], eb_1 = P.eb[Hv + j], eb_2 = P.eb[2 * Hv + j], eb_3 = P.eb[3 * Hv + j];
    const float db_0 = P.db[j], db_1 = P.db[Hv + j], db_2 = P.db[2 * Hv + j], db_3 = P.db[3 * Hv + j];
    const int eidx_e = P.eidx[b_e];
    float c_reg = 0.f, c_sv = 0.f;

    int ep = 0;

    // ================= encoder =================
    fill_w(P.eWhiT, P.eWloT);
    __syncthreads();
    const ushort_t* ihh = P.hz_hi;
    const ushort_t* ihl = P.hz_lo;
    for (int t = 0; t < Tv; t++) {
        // prefetch epilogue inputs (hide LLC latency under MFMA)
        int tk = P.etok[b_e * Tv + t];
        const float* wr = P.eWi + (size_t)tk * FH + j;
        float w0 = wr[0], w1 = wr[Hv], w2 = wr[2 * Hv], w3 = wr[3 * Hv];

        f32x4 acc = {0.f, 0.f, 0.f, 0.f};
#pragma unroll 4
        for (int kc = 0; kc < Hv; kc += 32) {
            int kq = (kc >> 3) + quad;
            bf16x8 ahi = *(const bf16x8*)(ihh + arow + kc);
            bf16x8 alo = *(const bf16x8*)(ihl + arow + kc);
            bf16x8 bh  = *(const bf16x8*)(&wlds[0][kq][cw][0]);
            bf16x8 bl2 = *(const bf16x8*)(&wlds[1][kq][cw][0]);
            acc = __builtin_amdgcn_mfma_f32_16x16x32_bf16(ahi, bh,  acc, 0, 0, 0);
            acc = __builtin_amdgcn_mfma_f32_16x16x32_bf16(alo, bh,  acc, 0, 0, 0);
            acc = __builtin_amdgcn_mfma_f32_16x16x32_bf16(ahi, bl2, acc, 0, 0, 0);
        }
        // C/D: col = n, row = quad*4 + r
#pragma unroll
        for (int r = 0; r < 4; r++)
            z_s[wm * 16 + quad * 4 + r][cw] = acc[r];
        __syncthreads();

        float z0 = eb_0 + w0 + z_s[bl][jl];
        float z1 = eb_1 + w1 + z_s[bl][8 + jl];
        float z2 = eb_2 + w2 + z_s[bl][16 + jl];
        float z3 = eb_3 + w3 + z_s[bl][24 + jl];
        float si = sigm(z0), sf = sigm(z1), so = sigm(z3);
        float gg = tanhf(z2);
        float cn = sf * c_reg + si * gg; c_reg = cn;
        float hn = so * tanhf(cn);
        ushort_t hh = f2bf(hn);
        ushort_t hl = f2bf(hn - bf2f(hh));
        size_t off = (size_t)b_e * Hv + j;
        ushort_t* oh = (t & 1) ? P.hb1_hi : P.hb0_hi;
        ushort_t* ol = (t & 1) ? P.hb1_lo : P.hb0_lo;
        oh[off] = hh; ol[off] = hl;
        if (t == eidx_e) {
            c_sv = cn;
            P.hsv_hi[off] = hh; P.hsv_lo[off] = hl;
        }
        gbar(P.bar, ep); ep++;
        ihh = oh; ihl = ol;
    }

    // ================= decoder =================
    __syncthreads();
    fill_w(P.dWhiT, P.dWloT);
    __syncthreads();
    c_reg = c_sv;
    ihh = P.hsv_hi; ihl = P.hsv_lo;
    for (int t = 0; t < TD; t++) {
        int tk = P.dtok[b_e * Tv + t];
        const float* wr = P.dWi + (size_t)tk * FH + j;
        float w0 = wr[0], w1 = wr[Hv], w2 = wr[2 * Hv], w3 = wr[3 * Hv];

        f32x4 acc = {0.f, 0.f, 0.f, 0.f};
#pragma unroll 4
        for (int kc = 0; kc < Hv; kc += 32) {
            int kq = (kc >> 3) + quad;
            bf16x8 ahi = *(const bf16x8*)(ihh + arow + kc);
            bf16x8 alo = *(const bf16x8*)(ihl + arow + kc);
            bf16x8 bh  = *(const bf16x8*)(&wlds[0][kq][cw][0]);
            bf16x8 bl2 = *(const bf16x8*)(&wlds[1][kq][cw][0]);
            acc = __builtin_amdgcn_mfma_f32_16x16x32_bf16(ahi, bh,  acc, 0, 0, 0);
            acc = __builtin_amdgcn_mfma_f32_16x16x32_bf16(alo, bh,  acc, 0, 0, 0);
            acc = __builtin_amdgcn_mfma_f32_16x16x32_bf16(ahi, bl2, acc, 0, 0, 0);
        }
#pragma unroll
        for (int r = 0; r < 4; r++)
            z_s[wm * 16 + quad * 4 + r][cw] = acc[r];
        __syncthreads();

        float z0 = db_0 + w0 + z_s[bl][jl];
        float z1 = db_1 + w1 + z_s[bl][8 + jl];
        float z2 = db_2 + w2 + z_s[bl][16 + jl];
        float z3 = db_3 + w3 + z_s[bl][24 + jl];
        float si = sigm(z0), sf = sigm(z1), so = sigm(z3);
        float gg = tanhf(z2);
        float cn = sf * c_reg + si * gg; c_reg = cn;
        float hn = so * tanhf(cn);
        ushort_t hh = f2bf(hn);
        ushort_t hl = f2bf(hn - bf2f(hh));
        size_t off = (size_t)b_e * Hv + j;
        ushort_t* oh = (t & 1) ? P.hb1_hi : P.hb0_hi;
        ushort_t* ol = (t & 1) ? P.hb1_lo : P.hb0_lo;
        oh[off] = hh; ol[off] = hl;
        P.hd_hi[(size_t)t * (Bv * Hv) + off] = hh;
        P.hd_lo[(size_t)t * (Bv * Hv) + off] = hl;
        gbar(P.bar, ep); ep++;
        ihh = oh; ihl = ol;
    }
}

// ---------------------------------------------------------------------------
// logits = hd @ dense_W + b : [32640,1024] x [1024,512], bf16x3 MFMA.
// ---------------------------------------------------------------------------
__global__ __launch_bounds__(256) void dense_mfma(
    const ushort_t* __restrict__ Ahi, const ushort_t* __restrict__ Alo,
    const ushort_t* __restrict__ WhiT, const ushort_t* __restrict__ WloT,
    const float* __restrict__ bias, float* __restrict__ out)
{
    const int tid = threadIdx.x;
    const int wave = tid >> 6, lane = tid & 63;
    const int wm = wave & 1, wn = wave >> 1;
    const int n = lane & 15, quad = lane >> 4;
    const int m0 = blockIdx.y * 32 + wm * 16;
    const int c0 = blockIdx.x * 64 + wn * 32;

    const size_t arow = (size_t)(m0 + n) * Hv + quad * 8;
    const size_t g0 = (size_t)(c0 + 0 + n) * Hv + quad * 8;
    const size_t g1 = (size_t)(c0 + 16 + n) * Hv + quad * 8;

    f32x4 acc0 = {0.f, 0.f, 0.f, 0.f}, acc1 = {0.f, 0.f, 0.f, 0.f};

#pragma unroll 2
    for (int kc = 0; kc < Hv; kc += 32) {
        bf16x8 ahi = *(const bf16x8*)(Ahi + arow + kc);
        bf16x8 alo = *(const bf16x8*)(Alo + arow + kc);
        bf16x8 b0h = *(const bf16x8*)(WhiT + g0 + kc);
        bf16x8 b0l = *(const bf16x8*)(WloT + g0 + kc);
        bf16x8 b1h = *(const bf16x8*)(WhiT + g1 + kc);
        bf16x8 b1l = *(const bf16x8*)(WloT + g1 + kc);
        acc0 = __builtin_amdgcn_mfma_f32_16x16x32_bf16(ahi, b0h, acc0, 0, 0, 0);
        acc1 = __builtin_amdgcn_mfma_f32_16x16x32_bf16(ahi, b1h, acc1, 0, 0, 0);
        acc0 = __builtin_amdgcn_mfma_f32_16x16x32_bf16(alo, b0h, acc0, 0, 0, 0);
        acc1 = __builtin_amdgcn_mfma_f32_16x16x32_bf16(alo, b1h, acc1, 0, 0, 0);
        acc0 = __builtin_amdgcn_mfma_f32_16x16x32_bf16(ahi, b0l, acc0, 0, 0, 0);
        acc1 = __builtin_amdgcn_mfma_f32_16x16x32_bf16(ahi, b1l, acc1, 0, 0, 0);
    }

#pragma unroll
    for (int r = 0; r < 4; r++) {
        int row = m0 + quad * 4 + r;
        int tt = row >> 7, bb = row & 127;
        size_t o = ((size_t)bb * TD + tt) * Vv;
        int col0 = c0 + n, col1 = c0 + 16 + n;
        out[o + col0] = acc0[r] + bias[col0];
        out[o + col1] = acc1[r] + bias[col1];
    }
}

// ---------------------------------------------------------------------------
extern "C" void kernel_launch(void* const* d_in, const int* in_sizes, int n_in,
                              void* d_out, int out_size, void* d_ws, size_t ws_size,
                              hipStream_t stream)
{
    const float* enc_in  = (const float*)d_in[0];
    const float* dec_in  = (const float*)d_in[1];
    const float* enc_Wi  = (const float*)d_in[2];
    const float* enc_Wh  = (const float*)d_in[3];
    const float* enc_b   = (const float*)d_in[4];
    const float* dec_Wi  = (const float*)d_in[5];
    const float* dec_Wh  = (const float*)d_in[6];
    const float* dec_b   = (const float*)d_in[7];
    const float* dense_W = (const float*)d_in[8];
    const float* dense_b = (const float*)d_in[9];
    float* out = (float*)d_out;

    char* wp = (char*)d_ws;
    auto take = [&](size_t bytes) -> char* {
        char* p = wp;
        wp += (bytes + 255) & ~(size_t)255;
        return p;
    };

    ushort_t* hd_hi = (ushort_t*)take((size_t)TD * Bv * Hv * 2);
    ushort_t* hd_lo = (ushort_t*)take((size_t)TD * Bv * Hv * 2);
    ushort_t* eWhi  = (ushort_t*)take((size_t)FH * Hv * 2);
    ushort_t* eWlo  = (ushort_t*)take((size_t)FH * Hv * 2);
    ushort_t* dWhi  = (ushort_t*)take((size_t)FH * Hv * 2);
    ushort_t* dWlo  = (ushort_t*)take((size_t)FH * Hv * 2);
    ushort_t* nWhi  = (ushort_t*)take((size_t)Vv * Hv * 2);
    ushort_t* nWlo  = (ushort_t*)take((size_t)Vv * Hv * 2);
    ushort_t* hzhi  = (ushort_t*)take((size_t)Bv * Hv * 2);
    ushort_t* hzlo  = (ushort_t*)take((size_t)Bv * Hv * 2);
    ushort_t* hb0h  = (ushort_t*)take((size_t)Bv * Hv * 2);
    ushort_t* hb0l  = (ushort_t*)take((size_t)Bv * Hv * 2);
    ushort_t* hb1h  = (ushort_t*)take((size_t)Bv * Hv * 2);
    ushort_t* hb1l  = (ushort_t*)take((size_t)Bv * Hv * 2);
    ushort_t* hshi  = (ushort_t*)take((size_t)Bv * Hv * 2);
    ushort_t* hslo  = (ushort_t*)take((size_t)Bv * Hv * 2);
    int*      etok  = (int*)take((size_t)Bv * Tv * 4);
    int*      dtok  = (int*)take((size_t)Bv * Tv * 4);
    int*      eidx  = (int*)take((size_t)Bv * 4);
    int*      bar   = (int*)take(4096);

    // --- preprocess ---------------------------------------------------------
    wsplit_t<<<dim3(FH / 64, Hv / 32), 256, 0, stream>>>(enc_Wh, Hv, FH, eWhi, eWlo);
    wsplit_t<<<dim3(FH / 64, Hv / 32), 256, 0, stream>>>(dec_Wh, Hv, FH, dWhi, dWlo);
    wsplit_t<<<dim3(Vv / 64, Hv / 32), 256, 0, stream>>>(dense_W, Hv, Vv, nWhi, nWlo);
    extract_tokens<<<Bv * Tv / 4, 256, 0, stream>>>(enc_in, etok);
    extract_tokens<<<Bv * Tv / 4, 256, 0, stream>>>(dec_in, dtok);
    find_eos<<<1, Bv, 0, stream>>>(etok, eidx);

    hipMemsetAsync(hzhi, 0, (size_t)Bv * Hv * 2, stream);
    hipMemsetAsync(hzlo, 0, (size_t)Bv * Hv * 2, stream);
    hipMemsetAsync(bar, 0, 4096, stream);

    // --- persistent fused LSTM (1 barrier/step, minimal coherent data) ------
    PArgs pa;
    pa.eWhiT = eWhi; pa.eWloT = eWlo; pa.dWhiT = dWhi; pa.dWloT = dWlo;
    pa.eWi = enc_Wi; pa.dWi = dec_Wi; pa.eb = enc_b; pa.db = dec_b;
    pa.etok = etok; pa.dtok = dtok; pa.eidx = eidx;
    pa.hz_hi = hzhi; pa.hz_lo = hzlo;
    pa.hb0_hi = hb0h; pa.hb0_lo = hb0l; pa.hb1_hi = hb1h; pa.hb1_lo = hb1l;
    pa.hsv_hi = hshi; pa.hsv_lo = hslo;
    pa.hd_hi = hd_hi; pa.hd_lo = hd_lo;
    pa.bar = bar;

    lstm_persist<<<dim3(256), dim3(512), 0, stream>>>(pa);

    // --- dense head ---------------------------------------------------------
    dense_mfma<<<dim3(Vv / 64, (TD * Bv) / 32), 256, 0, stream>>>(
        hd_hi, hd_lo, nWhi, nWlo, dense_b, out);
}

// Round 7
// 17167.618 us; speedup vs baseline: 2.1108x; 2.1108x over previous
//
#include <hip/hip_runtime.h>

#define Bv 128
#define Tv 256
#define Vv 512
#define Hv 1024
#define FH 4096   // 4*H
#define TD 255    // T-1 decoder steps

typedef unsigned short ushort_t;
typedef __attribute__((ext_vector_type(8))) short bf16x8;
typedef __attribute__((ext_vector_type(4))) float f32x4;

__device__ __forceinline__ ushort_t f2bf(float f) {
    unsigned u = __float_as_uint(f);
    unsigned r = (u + 0x7fffu + ((u >> 16) & 1u)) >> 16;
    return (ushort_t)r;
}
__device__ __forceinline__ float bf2f(ushort_t h) {
    return __uint_as_float(((unsigned)h) << 16);
}
__device__ __forceinline__ float sigm(float x) {
    return 1.0f / (1.0f + expf(-x));
}

// ---------------------------------------------------------------------------
// Split W [K][N] fp32 into transposed hi/lo bf16 [N][K]
// grid (N/64, K/32), 256 threads
// ---------------------------------------------------------------------------
__global__ __launch_bounds__(256) void wsplit_t(
    const float* __restrict__ W, int K, int N,
    ushort_t* __restrict__ hiT, ushort_t* __restrict__ loT)
{
    __shared__ float ts[32][65];
    const int n0 = blockIdx.x * 64, k0 = blockIdx.y * 32;
    const int tid = threadIdx.x;
#pragma unroll
    for (int i = 0; i < 8; i++) {
        int f = tid + i * 256;
        int k = f >> 6, nn = f & 63;
        ts[k][nn] = W[(size_t)(k0 + k) * N + n0 + nn];
    }
    __syncthreads();
#pragma unroll
    for (int i = 0; i < 8; i++) {
        int f = tid + i * 256;
        int nn = f >> 5, k = f & 31;
        float v = ts[k][nn];
        ushort_t h = f2bf(v);
        ushort_t l = f2bf(v - bf2f(h));
        size_t o = (size_t)(n0 + nn) * K + k0 + k;
        hiT[o] = h;
        loT[o] = l;
    }
}

// ---------------------------------------------------------------------------
// Pack Wi rows + bias into float4 table: Wp[v][j] = {Wi[v][g*H+j]+bias[g*H+j]}
// grid (512), 1024 threads
// ---------------------------------------------------------------------------
__global__ __launch_bounds__(1024) void wi_pack(
    const float* __restrict__ Wi, const float* __restrict__ bias,
    float* __restrict__ Wp)
{
    const int v = blockIdx.x, j = threadIdx.x;
    f32x4 o;
    o[0] = Wi[(size_t)v * FH + j]          + bias[j];
    o[1] = Wi[(size_t)v * FH + Hv + j]     + bias[Hv + j];
    o[2] = Wi[(size_t)v * FH + 2 * Hv + j] + bias[2 * Hv + j];
    o[3] = Wi[(size_t)v * FH + 3 * Hv + j] + bias[3 * Hv + j];
    *(f32x4*)(Wp + ((size_t)v * 1024 + j) * 4) = o;
}

// ---------------------------------------------------------------------------
// One-hot [rows][512] -> token index. One wave per row.
// ---------------------------------------------------------------------------
__global__ __launch_bounds__(256) void extract_tokens(
    const float* __restrict__ x, int* __restrict__ tok)
{
    int row = blockIdx.x * 4 + (threadIdx.x >> 6);
    int lane = threadIdx.x & 63;
    const float* p = x + (size_t)row * Vv;
    int found = -1;
#pragma unroll
    for (int i = 0; i < 8; i++)
        if (p[lane + i * 64] > 0.5f) found = lane + i * 64;
#pragma unroll
    for (int off = 32; off > 0; off >>= 1) {
        int o = __shfl_down(found, off);
        found = found > o ? found : o;
    }
    if (lane == 0) tok[row] = found;
}

// ---------------------------------------------------------------------------
__global__ void find_eos(const int* __restrict__ tok, int* __restrict__ idx)
{
    int b = threadIdx.x;
    int first = Tv - 1;
    for (int t = Tv - 1; t >= 0; t--)
        if (tok[b * Tv + t] == 1) first = t;
    idx[b] = first;
}

// ---------------------------------------------------------------------------
// One LSTM step. grid (64 j-tiles, 2 b-halves) = 128 blocks, 1024 thr (16 wv).
// Block tile: 64 batches x 64 z-cols (4 gates x 16 j), K=1024.
// Waves: wk = wave>>2 (K-quarter 256), wm = (wave>>1)&1 (32-row half),
//        wn = wave&1 (32-col half); each wave: 2 m-tiles x 2 col-frags.
// Weight dedup: 2 b-halves of a j-tile share the same XCD (id%8 = bx%8) ->
// weight slice L2-shared within the step. Traffic 96 -> 64 MB/step vs R3.
// Epilogue: 1 (b,j) elem/thread; Wi+bias via one packed float4 load.
// ---------------------------------------------------------------------------
__global__ __launch_bounds__(1024) void lstm_step(
    const ushort_t* __restrict__ WhiT, const ushort_t* __restrict__ WloT, // [4096][1024]
    const float* __restrict__ Wp,      // [512][1024][4] packed Wi+bias
    const int* __restrict__ tok, int t,
    const ushort_t* __restrict__ hin_hi, const ushort_t* __restrict__ hin_lo, // [B][H]
    ushort_t* __restrict__ hout_hi, ushort_t* __restrict__ hout_lo,
    const float* __restrict__ c_in, float* __restrict__ c_out,  // [B][H] fp32
    ushort_t* __restrict__ hex_hi, ushort_t* __restrict__ hex_lo,   // nullable
    const int* __restrict__ save_idx,                               // nullable
    float* __restrict__ c_save, ushort_t* __restrict__ hs_hi, ushort_t* __restrict__ hs_lo)
{
    __shared__ float z_s[4][64][66];   // 67.6 KB
    const int tid = threadIdx.x;
    const int wave = tid >> 6, lane = tid & 63;
    const int wk = wave >> 2;            // K-quarter
    const int wm = (wave >> 1) & 1;      // row half
    const int wn = wave & 1;             // col half
    const int n = lane & 15, quad = lane >> 4;
    const int j0 = blockIdx.x * 16;
    const int b0 = blockIdx.y * 64;
    const int k0 = wk * 256;

    // ---- epilogue prefetch: 1 (b,j) per thread ----------------------------
    const int bl = tid >> 4, jl = tid & 15;
    const int b_e = b0 + bl, j = j0 + jl;
    const int tk = tok[b_e * Tv + t];
    const f32x4 wv = *(const f32x4*)(Wp + ((size_t)tk * 1024 + j) * 4);
    const size_t off = (size_t)b_e * Hv + j;
    const float c_old = c_in[off];
    const int sidx = save_idx ? save_idx[b_e] : -1;

    // ---- MFMA: rows (b0+wm*32, 2x16) x cols (wn*32, 2x16) x K-quarter -----
    const size_t a0 = (size_t)(b0 + wm * 32 + n) * Hv + k0 + quad * 8;
    const size_t a1 = a0 + (size_t)16 * Hv;
    const size_t g0 = (size_t)((wn * 2 + 0) * Hv + j0 + n) * Hv + k0 + quad * 8;
    const size_t g1 = (size_t)((wn * 2 + 1) * Hv + j0 + n) * Hv + k0 + quad * 8;

    f32x4 acc00 = {0,0,0,0}, acc01 = {0,0,0,0}, acc10 = {0,0,0,0}, acc11 = {0,0,0,0};

#pragma unroll 2
    for (int kc = 0; kc < 256; kc += 32) {
        bf16x8 a0h = *(const bf16x8*)(hin_hi + a0 + kc);
        bf16x8 a0l = *(const bf16x8*)(hin_lo + a0 + kc);
        bf16x8 a1h = *(const bf16x8*)(hin_hi + a1 + kc);
        bf16x8 a1l = *(const bf16x8*)(hin_lo + a1 + kc);
        bf16x8 b0h = *(const bf16x8*)(WhiT + g0 + kc);
        bf16x8 b0l = *(const bf16x8*)(WloT + g0 + kc);
        bf16x8 b1h = *(const bf16x8*)(WhiT + g1 + kc);
        bf16x8 b1l = *(const bf16x8*)(WloT + g1 + kc);
        acc00 = __builtin_amdgcn_mfma_f32_16x16x32_bf16(a0h, b0h, acc00, 0, 0, 0);
        acc01 = __builtin_amdgcn_mfma_f32_16x16x32_bf16(a0h, b1h, acc01, 0, 0, 0);
        acc10 = __builtin_amdgcn_mfma_f32_16x16x32_bf16(a1h, b0h, acc10, 0, 0, 0);
        acc11 = __builtin_amdgcn_mfma_f32_16x16x32_bf16(a1h, b1h, acc11, 0, 0, 0);
        acc00 = __builtin_amdgcn_mfma_f32_16x16x32_bf16(a0l, b0h, acc00, 0, 0, 0);
        acc01 = __builtin_amdgcn_mfma_f32_16x16x32_bf16(a0l, b1h, acc01, 0, 0, 0);
        acc10 = __builtin_amdgcn_mfma_f32_16x16x32_bf16(a1l, b0h, acc10, 0, 0, 0);
        acc11 = __builtin_amdgcn_mfma_f32_16x16x32_bf16(a1l, b1h, acc11, 0, 0, 0);
        acc00 = __builtin_amdgcn_mfma_f32_16x16x32_bf16(a0h, b0l, acc00, 0, 0, 0);
        acc01 = __builtin_amdgcn_mfma_f32_16x16x32_bf16(a0h, b1l, acc01, 0, 0, 0);
        acc10 = __builtin_amdgcn_mfma_f32_16x16x32_bf16(a1h, b0l, acc10, 0, 0, 0);
        acc11 = __builtin_amdgcn_mfma_f32_16x16x32_bf16(a1h, b1l, acc11, 0, 0, 0);
    }

    // C/D: col = lane&15, row = quad*4 + r
    {
        const int rb = wm * 32 + quad * 4;
        const int cc = wn * 32 + n;
#pragma unroll
        for (int r = 0; r < 4; r++) {
            z_s[wk][rb + r][cc]           = acc00[r];
            z_s[wk][rb + r][cc + 16]      = acc01[r];
            z_s[wk][rb + 16 + r][cc]      = acc10[r];
            z_s[wk][rb + 16 + r][cc + 16] = acc11[r];
        }
    }
    __syncthreads();

    // ---- epilogue ----------------------------------------------------------
    {
        float z0 = wv[0], z1 = wv[1], z2 = wv[2], z3 = wv[3];
#pragma unroll
        for (int q = 0; q < 4; q++) {
            z0 += z_s[q][bl][jl];
            z1 += z_s[q][bl][16 + jl];
            z2 += z_s[q][bl][32 + jl];
            z3 += z_s[q][bl][48 + jl];
        }
        float si = sigm(z0), sf = sigm(z1), so = sigm(z3);
        float gg = tanhf(z2);
        float cn = sf * c_old + si * gg;
        float hn = so * tanhf(cn);
        c_out[off] = cn;
        ushort_t hh = f2bf(hn);
        ushort_t hl = f2bf(hn - bf2f(hh));
        hout_hi[off] = hh;
        hout_lo[off] = hl;
        if (hex_hi) { hex_hi[off] = hh; hex_lo[off] = hl; }
        if (save_idx) {
            if (t == sidx) { c_save[off] = cn; hs_hi[off] = hh; hs_lo[off] = hl; }
        }
    }
}

// ---------------------------------------------------------------------------
// logits = hd @ dense_W + b : [32640,1024] x [1024,512], bf16x3 MFMA.
// grid (8, 1020), 256 threads; block 32 m x 64 n; wave 16 m x 32 n.
// ---------------------------------------------------------------------------
__global__ __launch_bounds__(256) void dense_mfma(
    const ushort_t* __restrict__ Ahi, const ushort_t* __restrict__ Alo, // [32640][1024]
    const ushort_t* __restrict__ WhiT, const ushort_t* __restrict__ WloT, // [512][1024]
    const float* __restrict__ bias, float* __restrict__ out)
{
    const int tid = threadIdx.x;
    const int wave = tid >> 6, lane = tid & 63;
    const int wm = wave & 1, wn = wave >> 1;
    const int n = lane & 15, quad = lane >> 4;
    const int m0 = blockIdx.y * 32 + wm * 16;
    const int c0 = blockIdx.x * 64 + wn * 32;

    const size_t arow = (size_t)(m0 + n) * Hv + quad * 8;
    const size_t g0 = (size_t)(c0 + 0 + n) * Hv + quad * 8;
    const size_t g1 = (size_t)(c0 + 16 + n) * Hv + quad * 8;

    f32x4 acc0 = {0.f, 0.f, 0.f, 0.f}, acc1 = {0.f, 0.f, 0.f, 0.f};

#pragma unroll 2
    for (int kc = 0; kc < Hv; kc += 32) {
        bf16x8 ahi = *(const bf16x8*)(Ahi + arow + kc);
        bf16x8 alo = *(const bf16x8*)(Alo + arow + kc);
        bf16x8 b0h = *(const bf16x8*)(WhiT + g0 + kc);
        bf16x8 b0l = *(const bf16x8*)(WloT + g0 + kc);
        bf16x8 b1h = *(const bf16x8*)(WhiT + g1 + kc);
        bf16x8 b1l = *(const bf16x8*)(WloT + g1 + kc);
        acc0 = __builtin_amdgcn_mfma_f32_16x16x32_bf16(ahi, b0h, acc0, 0, 0, 0);
        acc1 = __builtin_amdgcn_mfma_f32_16x16x32_bf16(ahi, b1h, acc1, 0, 0, 0);
        acc0 = __builtin_amdgcn_mfma_f32_16x16x32_bf16(alo, b0h, acc0, 0, 0, 0);
        acc1 = __builtin_amdgcn_mfma_f32_16x16x32_bf16(alo, b1h, acc1, 0, 0, 0);
        acc0 = __builtin_amdgcn_mfma_f32_16x16x32_bf16(ahi, b0l, acc0, 0, 0, 0);
        acc1 = __builtin_amdgcn_mfma_f32_16x16x32_bf16(ahi, b1l, acc1, 0, 0, 0);
    }

#pragma unroll
    for (int r = 0; r < 4; r++) {
        int row = m0 + quad * 4 + r;
        int tt = row >> 7, bb = row & 127;
        size_t o = ((size_t)bb * TD + tt) * Vv;
        int col0 = c0 + n, col1 = c0 + 16 + n;
        out[o + col0] = acc0[r] + bias[col0];
        out[o + col1] = acc1[r] + bias[col1];
    }
}

// ---------------------------------------------------------------------------
extern "C" void kernel_launch(void* const* d_in, const int* in_sizes, int n_in,
                              void* d_out, int out_size, void* d_ws, size_t ws_size,
                              hipStream_t stream)
{
    const float* enc_in  = (const float*)d_in[0];
    const float* dec_in  = (const float*)d_in[1];
    const float* enc_Wi  = (const float*)d_in[2];
    const float* enc_Wh  = (const float*)d_in[3];
    const float* enc_b   = (const float*)d_in[4];
    const float* dec_Wi  = (const float*)d_in[5];
    const float* dec_Wh  = (const float*)d_in[6];
    const float* dec_b   = (const float*)d_in[7];
    const float* dense_W = (const float*)d_in[8];
    const float* dense_b = (const float*)d_in[9];
    float* out = (float*)d_out;

    char* wp = (char*)d_ws;
    auto take = [&](size_t bytes) -> char* {
        char* p = wp;
        wp += (bytes + 255) & ~(size_t)255;
        return p;
    };

    ushort_t* hd_hi = (ushort_t*)take((size_t)TD * Bv * Hv * 2);
    ushort_t* hd_lo = (ushort_t*)take((size_t)TD * Bv * Hv * 2);
    ushort_t* eWhi  = (ushort_t*)take((size_t)FH * Hv * 2);
    ushort_t* eWlo  = (ushort_t*)take((size_t)FH * Hv * 2);
    ushort_t* dWhi  = (ushort_t*)take((size_t)FH * Hv * 2);
    ushort_t* dWlo  = (ushort_t*)take((size_t)FH * Hv * 2);
    ushort_t* nWhi  = (ushort_t*)take((size_t)Vv * Hv * 2);
    ushort_t* nWlo  = (ushort_t*)take((size_t)Vv * Hv * 2);
    float*    eWp   = (float*)take((size_t)Vv * Hv * 4 * 4);   // packed Wi+bias
    float*    dWp   = (float*)take((size_t)Vv * Hv * 4 * 4);
    ushort_t* hbh0  = (ushort_t*)take((size_t)Bv * Hv * 2);
    ushort_t* hbl0  = (ushort_t*)take((size_t)Bv * Hv * 2);
    ushort_t* hbh1  = (ushort_t*)take((size_t)Bv * Hv * 2);
    ushort_t* hbl1  = (ushort_t*)take((size_t)Bv * Hv * 2);
    ushort_t* hshi  = (ushort_t*)take((size_t)Bv * Hv * 2);
    ushort_t* hslo  = (ushort_t*)take((size_t)Bv * Hv * 2);
    float*    c_state = (float*)take((size_t)Bv * Hv * 4);
    float*    c_save  = (float*)take((size_t)Bv * Hv * 4);
    int*      etok  = (int*)take((size_t)Bv * Tv * 4);
    int*      dtok  = (int*)take((size_t)Bv * Tv * 4);
    int*      eidx  = (int*)take((size_t)Bv * 4);

    ushort_t* hbh[2] = {hbh0, hbh1};
    ushort_t* hbl[2] = {hbl0, hbl1};

    // --- preprocess ---------------------------------------------------------
    wsplit_t<<<dim3(FH / 64, Hv / 32), 256, 0, stream>>>(enc_Wh, Hv, FH, eWhi, eWlo);
    wsplit_t<<<dim3(FH / 64, Hv / 32), 256, 0, stream>>>(dec_Wh, Hv, FH, dWhi, dWlo);
    wsplit_t<<<dim3(Vv / 64, Hv / 32), 256, 0, stream>>>(dense_W, Hv, Vv, nWhi, nWlo);
    wi_pack<<<dim3(Vv), 1024, 0, stream>>>(enc_Wi, enc_b, eWp);
    wi_pack<<<dim3(Vv), 1024, 0, stream>>>(dec_Wi, dec_b, dWp);
    extract_tokens<<<Bv * Tv / 4, 256, 0, stream>>>(enc_in, etok);
    extract_tokens<<<Bv * Tv / 4, 256, 0, stream>>>(dec_in, dtok);
    find_eos<<<1, Bv, 0, stream>>>(etok, eidx);

    hipMemsetAsync(hbh0, 0, (size_t)Bv * Hv * 2, stream);
    hipMemsetAsync(hbl0, 0, (size_t)Bv * Hv * 2, stream);
    hipMemsetAsync(c_state, 0, (size_t)Bv * Hv * 4, stream);

    // --- encoder: 256 steps, save state at t == eos_idx[b] ------------------
    for (int t = 0; t < Tv; t++) {
        lstm_step<<<dim3(64, 2), 1024, 0, stream>>>(
            eWhi, eWlo, eWp, etok, t,
            hbh[t & 1], hbl[t & 1], hbh[(t + 1) & 1], hbl[(t + 1) & 1],
            c_state, c_state, nullptr, nullptr, eidx, c_save, hshi, hslo);
    }

    // --- decoder: 255 steps; t=0 reads saved state directly -----------------
    for (int t = 0; t < TD; t++) {
        const ushort_t* ih = (t == 0) ? hshi : hbh[t & 1];
        const ushort_t* il = (t == 0) ? hslo : hbl[t & 1];
        const float*    ci = (t == 0) ? c_save : c_state;
        lstm_step<<<dim3(64, 2), 1024, 0, stream>>>(
            dWhi, dWlo, dWp, dtok, t,
            ih, il, hbh[(t + 1) & 1], hbl[(t + 1) & 1],
            ci, c_state, hd_hi + (size_t)t * Bv * Hv, hd_lo + (size_t)t * Bv * Hv,
            nullptr, nullptr, nullptr, nullptr);
    }

    // --- dense head ---------------------------------------------------------
    dense_mfma<<<dim3(Vv / 64, (TD * Bv) / 32), 256, 0, stream>>>(
        hd_hi, hd_lo, nWhi, nWlo, dense_b, out);
}